// Round 1
// baseline (140.801 us; speedup 1.0000x reference)
//
#include <hip/hip_runtime.h>
#include <hip/hip_bf16.h>

#define NN 8192
#define INF_ 512
#define OUTF 64
#define ALPHA_ 0.2f
#define CAP 2048

// Kernel A: Wh = h@W; f1 = Wh@a1; f2 = Wh@a2.
// One wave per row: lane = output feature. h row staged in LDS, W read from L2.
__global__ __launch_bounds__(256) void gat_wh_kernel(
    const float* __restrict__ h, const float* __restrict__ W,
    const float* __restrict__ a, float* __restrict__ Wh,
    float* __restrict__ f1, float* __restrict__ f2)
{
    __shared__ float sh[4][INF_];
    const int t = threadIdx.x;
    const int w = t >> 6, l = t & 63;
    const int row = blockIdx.x * 4 + w;

    // stage h row (512 floats = 128 float4) into this wave's LDS slab
    const float4* hv = (const float4*)(h + (size_t)row * INF_);
    float4* shv = (float4*)sh[w];
    shv[l]      = hv[l];
    shv[l + 64] = hv[l + 64];
    __syncthreads();

    float acc = 0.f;
    #pragma unroll 8
    for (int k = 0; k < INF_; ++k) {
        acc += sh[w][k] * W[k * OUTF + l];   // W row read coalesced, L2-hot
    }
    Wh[(size_t)row * OUTF + l] = acc;

    float v1 = acc * a[l];
    float v2 = acc * a[64 + l];
    #pragma unroll
    for (int m = 32; m >= 1; m >>= 1) {
        v1 += __shfl_xor(v1, m, 64);
        v2 += __shfl_xor(v2, m, 64);
    }
    if (l == 0) { f1[row] = v1; f2[row] = v2; }
}

// Kernel B: one block per row i. Scan adj row (float4, coalesced), build
// deterministic edge list in LDS via exclusive scan, online max, then
// feature-parallel weighted gather of Wh rows + softmax normalize + ELU.
__global__ __launch_bounds__(256) void gat_attn_kernel(
    const float* __restrict__ adj, const float* __restrict__ Wh,
    const float* __restrict__ f1, const float* __restrict__ f2,
    float* __restrict__ out)
{
    __shared__ int   s_idx[CAP];
    __shared__ float s_f2[CAP];
    __shared__ int   s_wsum[4];
    __shared__ float s_wmax[4];
    __shared__ float s_ps[4];
    __shared__ float s_red[256];

    const int i = blockIdx.x;
    const int t = threadIdx.x;
    const int w = t >> 6, l = t & 63;

    // --- phase 1: scan my 32 columns of adj row i ---
    const float4* arow = (const float4*)(adj + (size_t)i * NN);
    float4 va[8];
    const int base4 = t * 8;          // thread t covers cols [t*32, t*32+32)
    #pragma unroll
    for (int q = 0; q < 8; ++q) va[q] = arow[base4 + q];

    int cnt = 0;
    #pragma unroll
    for (int q = 0; q < 8; ++q) {
        cnt += (va[q].x > 0.f) + (va[q].y > 0.f) + (va[q].z > 0.f) + (va[q].w > 0.f);
    }

    // wave-level inclusive scan of counts
    int inc = cnt;
    #pragma unroll
    for (int d = 1; d < 64; d <<= 1) {
        int v = __shfl_up(inc, d, 64);
        if (l >= d) inc += v;
    }
    if (l == 63) s_wsum[w] = inc;
    __syncthreads();
    int woff = 0;
    #pragma unroll
    for (int ww = 0; ww < 4; ++ww) { if (ww < w) woff += s_wsum[ww]; }
    const int total = s_wsum[0] + s_wsum[1] + s_wsum[2] + s_wsum[3];
    int off = woff + inc - cnt;       // exclusive offset, deterministic order

    // write edge list, gather f2[j] (L2-hot, 32 KB), track local max
    float lmax = -1e30f;
    const int col = t * 32;
    #pragma unroll
    for (int q = 0; q < 8; ++q) {
        float vals[4] = {va[q].x, va[q].y, va[q].z, va[q].w};
        #pragma unroll
        for (int r = 0; r < 4; ++r) {
            if (vals[r] > 0.f) {
                const int j = col + q * 4 + r;
                const float fj = f2[j];
                if (off < CAP) { s_idx[off] = j; s_f2[off] = fj; }
                ++off;
                lmax = fmaxf(lmax, fj);
            }
        }
    }

    // block max of f2 over edges
    #pragma unroll
    for (int m = 32; m >= 1; m >>= 1) lmax = fmaxf(lmax, __shfl_xor(lmax, m, 64));
    if (l == 0) s_wmax[w] = lmax;
    __syncthreads();   // also publishes s_idx/s_f2

    const float mf2 = fmaxf(fmaxf(s_wmax[0], s_wmax[1]), fmaxf(s_wmax[2], s_wmax[3]));
    const float f1i = f1[i];
    const float xm  = f1i + mf2;
    const float emax = xm > 0.f ? xm : ALPHA_ * xm;   // lrelu monotone -> row max

    const int cnt_tot = total < CAP ? total : CAP;

    // --- phase 2: 4 edge-groups x 64 feature lanes ---
    float acc = 0.f, ps = 0.f;
    for (int e = w; e < cnt_tot; e += 4) {
        const int j = s_idx[e];
        float x = f1i + s_f2[e];
        x = x > 0.f ? x : ALPHA_ * x;
        const float p = __expf(x - emax);
        ps  += p;
        acc += p * Wh[(size_t)j * OUTF + l];   // 256 B coalesced gather, L2-hit
    }
    s_red[t] = acc;
    if (l == 0) s_ps[w] = ps;
    __syncthreads();

    if (t < 64) {
        const float tot = s_red[t] + s_red[64 + t] + s_red[128 + t] + s_red[192 + t];
        const float s   = s_ps[0] + s_ps[1] + s_ps[2] + s_ps[3];
        const float hp  = tot / s;
        const float o   = hp > 0.f ? hp : (__expf(hp) - 1.f);
        out[(size_t)i * OUTF + t] = o;
    }
}

extern "C" void kernel_launch(void* const* d_in, const int* in_sizes, int n_in,
                              void* d_out, int out_size, void* d_ws, size_t ws_size,
                              hipStream_t stream) {
    const float* h   = (const float*)d_in[0];
    const float* adj = (const float*)d_in[1];
    const float* W   = (const float*)d_in[2];
    const float* a   = (const float*)d_in[3];
    float* out = (float*)d_out;

    float* Wh = (float*)d_ws;                      // 8192*64 floats = 2 MB
    float* f1 = Wh + (size_t)NN * OUTF;            // 32 KB
    float* f2 = f1 + NN;                           // 32 KB

    gat_wh_kernel<<<NN / 4, 256, 0, stream>>>(h, W, a, Wh, f1, f2);
    gat_attn_kernel<<<NN, 256, 0, stream>>>(adj, Wh, f1, f2, out);
}